// Round 12
// baseline (77.624 us; speedup 1.0000x reference)
//
#include <hip/hip_runtime.h>
#include <hip/hip_bf16.h>
#include <math.h>

#define B_   16
#define N_   32
#define I_   1152
#define DIN  16
#define D_   64
#define TI   16            // i's per k_xhat block
#define IB   (I_/TI)       // 72 i-tiles
#define IC   16            // i-chunks in routing (72 i each)
#define BND  (B_*N_*D_)    // 32768

#if __has_builtin(__builtin_amdgcn_exp2f)
#define EXP2(x) __builtin_amdgcn_exp2f(x)
#else
#define EXP2(x) exp2f(x)
#endif

#define LOG2E 1.4426950408889634f

typedef __attribute__((ext_vector_type(8))) short short8v;
typedef __attribute__((ext_vector_type(4))) float f32x4;
typedef __attribute__((ext_vector_type(4))) unsigned int u32x4;
typedef __attribute__((ext_vector_type(2))) unsigned int u32x2;

__device__ __forceinline__ float squash1(float s) {
    float sq = s * s;
    return (sq / (1.0f + sq)) * s * rsqrtf(sq + 1e-9f);
}
__device__ __forceinline__ unsigned int bfh(float v) {
    return (unsigned int)__builtin_bit_cast(unsigned short, __float2bfloat16(v));
}
__device__ __forceinline__ float bff(unsigned int hi16) {
    return __builtin_bit_cast(float, hi16 << 16);
}

// async global->LDS, 16B per lane, dest = uniform base + lane*16 (linear)
#define GL16(g, l) __builtin_amdgcn_global_load_lds(                          \
    (const __attribute__((address_space(1))) void*)(g),                       \
    (__attribute__((address_space(3))) void*)(l), 16, 0, 0)

// K1: x_hat via MFMA; W staged through LDS with __builtin_amdgcn_global_load_lds
// (fire-and-forget DMA, no VGPR cost) in a 2-phase double-buffered loop:
// STAGE(quarter c+1) overlaps COMPUTE(quarter c), one barrier per quarter.
// R8-R11 showed hipcc sinks register prefetch (VGPR stayed 36-56) leaving the
// VMEM queue shallow; gload_lds bypasses the register allocator entirely.
// LDS W layout is linear [i][d][k]; bank conflicts on the A-frag ds_read_b128
// are fixed by rule-#21 both-sides swizzle: per-lane SOURCE address carries the
// inverse of the read-side XOR ( o ^ (((o>>6)>>1)&3)<<4 , bits 4-5 only ) =>
// 4 distinct addrs per bank-group = structural minimum (conflict-free).
// hi/lo W-residual: K 0..15 = W_hi bf16, 16..31 = W_lo residual, inputs
// duplicated -> fp32-grade W precision per mfma_f32_16x16x32_bf16.
// C-frag: col b=l&15, d = mt*16+(l>>4)*4+r. xh2 tile: element off = mt*256+4l.
__global__ __launch_bounds__(256, 4) void k_xhat(const float* __restrict__ inp,
                                                 const float* __restrict__ W,
                                                 unsigned short* __restrict__ xh2,
                                                 float* __restrict__ part) {
    __shared__ __align__(16) unsigned short xs[4096];   // inp tile bf16, swizzled (8KB)
    __shared__ __align__(16) float wls[2][4096];        // W dbuf, 2 x 16KB (4 i's each)

    const int bx = blockIdx.x;
    const int n  = bx / IB;
    const int ib = bx % IB;
    const int i0 = ib * TI;
    const int t  = threadIdx.x;
    const int l  = t & 63;
    const int mt = t >> 6;                 // wave id = d m-tile (0..3)
    const int ko = (l >> 4) & 1;           // k-octet
    const bool loHalf = (l >= 32);
    const int dd = mt * 16 + (l & 15);     // this lane's d row in W
    const int A_OFF   = (dd * 64 + ko * 32) ^ (((dd >> 1) & 3) << 4);
    const int lane_sw = (l * 16) ^ (((l >> 3) & 3) << 4);   // inverse swizzle, src side

    const char* Wn = (const char*)(W + (size_t)(n * I_ + i0) * 1024);  // 64KB block tile

    // stage quarter c (4 i's, 16KB) into wls[c&1]; wave mt stages quarter-of-i mt
#define STAGE(c) {                                                             \
        _Pragma("unroll")                                                      \
        for (int r = 0; r < 4; ++r) {                                          \
            const char* g = Wn + (size_t)((c) * 4 + r) * 4096 + mt * 1024 + lane_sw; \
            char* ld = (char*)wls[(c) & 1] + r * 4096 + mt * 1024;             \
            GL16(g, ld);                                                       \
        } }

#define COMPQ(c) {                                                             \
        const char* wq = (const char*)wls[(c) & 1];                            \
        _Pragma("unroll")                                                      \
        for (int j = 0; j < 4; ++j) {                                          \
            const int i = (c) * 4 + j;                                         \
            f32x4 wk0 = *(const f32x4*)(wq + j * 4096 + A_OFF);                \
            f32x4 wk1 = *(const f32x4*)(wq + j * 4096 + (A_OFF ^ 16));         \
            int xaddr = ((l & 15) * 512 + i * 32 + ko * 16) ^ (((l & 15) & 7) << 4); \
            short8v bfrag = *(const short8v*)((const char*)xs + xaddr);        \
            short8v afrag;                                                     \
            _Pragma("unroll")                                                  \
            for (int q = 0; q < 8; ++q) {                                      \
                float wv = (q < 4) ? wk0[q] : wk1[q - 4];                      \
                unsigned int hi = bfh(wv);                                     \
                unsigned int lo = bfh(wv - bff(hi));                           \
                afrag[q] = (short)(loHalf ? lo : hi);                          \
            }                                                                  \
            f32x4 acc = __builtin_amdgcn_mfma_f32_16x16x32_bf16(               \
                afrag, bfrag, (f32x4){0.f, 0.f, 0.f, 0.f}, 0, 0, 0);           \
            s0v += acc;                                                        \
            pk[i * 2]     = (bfh(acc[1]) << 16) | bfh(acc[0]);                 \
            pk[i * 2 + 1] = (bfh(acc[3]) << 16) | bfh(acc[2]);                 \
        } }

    STAGE(0)                               // fire-and-forget first quarter

    // ---- stage inputs -> bf16 LDS tile [b][il][ko][8], XOR-swizzled
    #pragma unroll
    for (int rep = 0; rep < 2; ++rep) {
        int s   = rep * 256 + t;           // 512 slots = 16b x 16il x 2ko
        int bb  = s >> 5;
        int il  = (s >> 1) & 15;
        int sko = s & 1;
        const float* src = inp + (size_t)bb * (I_ * DIN) + (size_t)(i0 + il) * DIN + sko * 8;
        f32x4 a0 = *(const f32x4*)src;
        f32x4 a1 = *(const f32x4*)(src + 4);
        u32x4 p;
        p.x = (bfh(a0.y) << 16) | bfh(a0.x);
        p.y = (bfh(a0.w) << 16) | bfh(a0.z);
        p.z = (bfh(a1.y) << 16) | bfh(a1.x);
        p.w = (bfh(a1.w) << 16) | bfh(a1.z);
        int base = (bb * 512 + il * 32 + sko * 16) ^ ((bb & 7) << 4);
        *(u32x4*)((char*)xs + base) = p;
    }
    __syncthreads();                       // quarter 0 + xs ready

    unsigned int pk[TI * 2];
    f32x4 s0v = {0.f, 0.f, 0.f, 0.f};

    STAGE(1) COMPQ(0) __syncthreads();
    STAGE(2) COMPQ(1) __syncthreads();
    STAGE(3) COMPQ(2) __syncthreads();
    COMPQ(3)
#undef STAGE
#undef COMPQ

    // ---- s0 partials (register-only), then fully-coalesced xh stores
    size_t pidx = (((size_t)ib * B_ + (l & 15)) * N_ + n) * 64 + mt * 16 + (l >> 4) * 4;
    *(f32x4*)(part + pidx) = s0v;

    #pragma unroll
    for (int i = 0; i < TI; ++i) {
        u32x2 v;
        v.x = pk[i * 2];
        v.y = pk[i * 2 + 1];
        size_t off = (size_t)(n * I_ + i0 + i) * 1024 + (size_t)t * 4;  // mt*256 + 4*l
        *reinterpret_cast<u32x2*>(xh2 + off) = v;
    }
}

// K2: coef = squash(mean over i of x_hat) — routing iteration 0.
// part layout [ib][b][n][d]; t packs (b,n,d) = coef index.
__global__ __launch_bounds__(256) void k_out0(const float* __restrict__ part,
                                              float* __restrict__ coef) {
    const int t = blockIdx.x * 256 + threadIdx.x;
    float s = 0.0f;
    for (int j = 0; j < IB; ++j) s += part[(size_t)j * BND + t];
    s *= (1.0f / (float)I_);
    coef[t] = squash1(s);
}

// K3: routing partial pass. xh2 tile is lane-ordered: thread t owns element
// offset 4t per i-tile => wave reads 512B CONTIGUOUS per i. Thread coords:
// b = t&15, d0 = (t>>4)*4. |logit|<=~50 -> exp2 safe without max-tracking.
// part2 layout [ic][n][b][d][2] = {z,a}.
__global__ __launch_bounds__(256) void k_rpart(const unsigned short* __restrict__ xh2,
                                               const float* __restrict__ coef,
                                               float* __restrict__ part2) {
    const int bx = blockIdx.x;
    const int n  = bx >> 4;
    const int ic = bx & 15;
    const int t  = threadIdx.x;
    const int b  = t & 15;
    const int d0 = (t >> 4) * 4;

    const unsigned short* base = xh2 + ((size_t)n * I_ + (size_t)ic * (I_ / IC)) * 1024
                               + (size_t)t * 4;
    f32x4 c4 = *(const f32x4*)(coef + ((size_t)b * N_ + n) * 64 + d0);
    float c2[4] = {c4.x * LOG2E, c4.y * LOG2E, c4.z * LOG2E, c4.w * LOG2E};
    float z[4] = {0, 0, 0, 0}, a[4] = {0, 0, 0, 0};

    #pragma unroll 8
    for (int i = 0; i < I_ / IC; ++i) {
        u32x2 u = *(const u32x2*)(base + (size_t)i * 1024);
        unsigned short s4[4] = {(unsigned short)(u.x & 0xffffu), (unsigned short)(u.x >> 16),
                                (unsigned short)(u.y & 0xffffu), (unsigned short)(u.y >> 16)};
        #pragma unroll
        for (int j = 0; j < 4; ++j) {
            float x = bff(s4[j]);
            float e = EXP2(x * c2[j]);
            z[j] += e;
            a[j] = fmaf(e, x, a[j]);
        }
    }

    size_t pidx = ((((size_t)ic * N_ + n) * 16 + b) * 64 + d0) * 2;
    f32x4 v0 = {z[0], a[0], z[1], a[1]};
    f32x4 v1 = {z[2], a[2], z[3], a[3]};
    *(f32x4*)(part2 + pidx)     = v0;
    *(f32x4*)(part2 + pidx + 4) = v1;
}

// K4: routing finisher. gid packs (n,b,d) matching part2 inner order.
// final=0: coef += squash(a/z). final=1: out[b][n][d] = squash(a/z).
__global__ __launch_bounds__(256) void k_rfin(const float* __restrict__ part2,
                                              const float* __restrict__ coefIn,
                                              float* __restrict__ outp,
                                              int final_) {
    const int gid = blockIdx.x * 256 + threadIdx.x;     // n*1024 + b*64 + d
    float Z = 0.0f, A = 0.0f;
    #pragma unroll
    for (int ic = 0; ic < IC; ++ic) {
        const float* p = part2 + ((size_t)ic * BND + gid) * 2;
        Z += p[0];
        A += p[1];
    }
    const int d = gid & 63, b = (gid >> 6) & 15, n = gid >> 10;
    const int ci = (b * N_ + n) * D_ + d;
    float o = squash1(A / Z);
    outp[ci] = final_ ? o : (coefIn[ci] + o);
}

extern "C" void kernel_launch(void* const* d_in, const int* in_sizes, int n_in,
                              void* d_out, int out_size, void* d_ws, size_t ws_size,
                              hipStream_t stream) {
    const float* inp = (const float*)d_in[0];
    const float* W   = (const float*)d_in[1];
    float* out = (float*)d_out;

    unsigned short* xh2 = (unsigned short*)d_ws;                    // 75,497,472 B
    float* part  = (float*)((char*)d_ws + 75497472);                //  9,437,184 B
    float* part2 = (float*)((char*)d_ws + 84934656);                //  4,194,304 B
    float* coef  = (float*)((char*)d_ws + 89128960);                //    131,072 B

    k_xhat<<<dim3(N_ * IB), dim3(256), 0, stream>>>(inp, W, xh2, part);
    k_out0<<<dim3(BND / 256), dim3(256), 0, stream>>>(part, coef);
    k_rpart<<<dim3(N_ * IC), dim3(256), 0, stream>>>(xh2, coef, part2);
    k_rfin <<<dim3(BND / 256), dim3(256), 0, stream>>>(part2, coef, coef, 0);
    k_rpart<<<dim3(N_ * IC), dim3(256), 0, stream>>>(xh2, coef, part2);
    k_rfin <<<dim3(BND / 256), dim3(256), 0, stream>>>(part2, coef, out, 1);
}

// Round 13
// 75.788 us; speedup vs baseline: 1.0242x; 1.0242x over previous
//
#include <hip/hip_runtime.h>
#include <hip/hip_bf16.h>
#include <math.h>

#define B_   16
#define N_   32
#define I_   1152
#define DIN  16
#define D_   64
#define TI   16            // i's per k_xhat block
#define IB   (I_/TI)       // 72 i-tiles
#define IC   16            // i-chunks in routing (72 i each)
#define BND  (B_*N_*D_)    // 32768

#if __has_builtin(__builtin_amdgcn_exp2f)
#define EXP2(x) __builtin_amdgcn_exp2f(x)
#else
#define EXP2(x) exp2f(x)
#endif

#define LOG2E 1.4426950408889634f

typedef __attribute__((ext_vector_type(8))) short short8v;
typedef __attribute__((ext_vector_type(4))) float f32x4;
typedef __attribute__((ext_vector_type(4))) unsigned int u32x4;
typedef __attribute__((ext_vector_type(2))) unsigned int u32x2;

__device__ __forceinline__ float squash1(float s) {
    float sq = s * s;
    return (sq / (1.0f + sq)) * s * rsqrtf(sq + 1e-9f);
}
__device__ __forceinline__ unsigned int bfh(float v) {
    return (unsigned int)__builtin_bit_cast(unsigned short, __float2bfloat16(v));
}
__device__ __forceinline__ float bff(unsigned int hi16) {
    return __builtin_bit_cast(float, hi16 << 16);
}
// HW packed fp32->bf16 RNE: dst[15:0]=bf16(a), dst[31:16]=bf16(b). 1 VALU op.
__device__ __forceinline__ unsigned int cvtpk(float a, float b) {
    unsigned int r;
    asm("v_cvt_pk_bf16_f32 %0, %1, %2" : "=v"(r) : "v"(a), "v"(b));
    return r;
}

// K1: x_hat via MFMA (R11 structure: TI=16, 2-deep reg-pipelined W stream,
// LDS-staged inputs, lane-order coalesced xh2 stores) with the bf16
// CONVERSION CHAIN CUT ~2x:
//  - A-frag hi half = fp32 bit-TRUNCATION packed by v_perm_b32 (1 op / 2
//    elems vs ~10 for the software-RNE path). Residual lo = RNE(w - trunc(w))
//    carries the correction: total A error ~2^-17, same accuracy class.
//  - lo pairs / input staging / acc packing via HW v_cvt_pk_bf16_f32.
// Rationale: ~70-80 VALU ops of software RNE per 5-cycle MFMA sat INSIDE the
// load->MFMA dep chain across R5-R12 (no pipe ever saturated; every load-
// structure probe was neutral). hi/lo residual: K 0..15 = W_hi, 16..31 =
// W_lo, inputs duplicated -> fp32-grade W per mfma_f32_16x16x32_bf16.
// C-frag: col b=l&15, d = mt*16+(l>>4)*4+r. xh2 tile: element off = mt*256+4l.
__global__ __launch_bounds__(256, 3) void k_xhat(const float* __restrict__ inp,
                                                 const float* __restrict__ W,
                                                 unsigned short* __restrict__ xh2,
                                                 float* __restrict__ part) {
    __shared__ __align__(16) unsigned short xs[4096];   // [b][il][ko][8] bf16, swizzled (8KB)
    const int bx = blockIdx.x;
    const int n  = bx / IB;
    const int ib = bx % IB;
    const int i0 = ib * TI;
    const int t  = threadIdx.x;
    const int l  = t & 63;
    const int mt = t >> 6;                 // wave id = d m-tile (0..3)
    const int row = l & 15;
    const int ko  = (l >> 4) & 1;          // k-octet for A/B frags
    const bool loHalf = (l >= 32);

    // ---- stage inputs -> bf16 LDS tile [b][il][ko][8], XOR-swizzled
    #pragma unroll
    for (int rep = 0; rep < 2; ++rep) {
        int s   = rep * 256 + t;           // 512 slots = 16b x 16il x 2ko
        int bb  = s >> 5;
        int il  = (s >> 1) & 15;
        int sko = s & 1;
        const float* src = inp + (size_t)bb * (I_ * DIN) + (size_t)(i0 + il) * DIN + sko * 8;
        f32x4 a0 = *(const f32x4*)src;
        f32x4 a1 = *(const f32x4*)(src + 4);
        u32x4 p;
        p.x = cvtpk(a0.x, a0.y);
        p.y = cvtpk(a0.z, a0.w);
        p.z = cvtpk(a1.x, a1.y);
        p.w = cvtpk(a1.z, a1.w);
        int base = (bb * 512 + il * 32 + sko * 16) ^ ((bb & 7) << 4);
        *(u32x4*)((char*)xs + base) = p;
    }
    __syncthreads();

    const float* wb = W + ((size_t)(n * I_ + i0) * 64 + mt * 16 + row) * 16 + ko * 8;

    unsigned int pk[TI * 2];
    f32x4 s0v = {0.f, 0.f, 0.f, 0.f};

#define LOADG(DST, C) {                                                        \
        _Pragma("unroll")                                                      \
        for (int j = 0; j < 4; ++j) {                                          \
            const f32x4* p = (const f32x4*)(wb + (size_t)((C) * 4 + j) * 1024);\
            DST[2 * j] = p[0]; DST[2 * j + 1] = p[1];                          \
        } }

#define COMPG(SRC, C) {                                                        \
        _Pragma("unroll")                                                      \
        for (int j = 0; j < 4; ++j) {                                          \
            const int i = (C) * 4 + j;                                         \
            f32x4 w0 = SRC[2 * j], w1 = SRC[2 * j + 1];                        \
            u32x4 b0 = __builtin_bit_cast(u32x4, w0);                          \
            u32x4 b1 = __builtin_bit_cast(u32x4, w1);                          \
            u32x4 ah, al;                                                      \
            ah.x = __builtin_amdgcn_perm(b0.y, b0.x, 0x07060302u);             \
            ah.y = __builtin_amdgcn_perm(b0.w, b0.z, 0x07060302u);             \
            ah.z = __builtin_amdgcn_perm(b1.y, b1.x, 0x07060302u);             \
            ah.w = __builtin_amdgcn_perm(b1.w, b1.z, 0x07060302u);             \
            float r0 = w0.x - __builtin_bit_cast(float, b0.x & 0xffff0000u);   \
            float r1 = w0.y - __builtin_bit_cast(float, b0.y & 0xffff0000u);   \
            float r2 = w0.z - __builtin_bit_cast(float, b0.z & 0xffff0000u);   \
            float r3 = w0.w - __builtin_bit_cast(float, b0.w & 0xffff0000u);   \
            float r4 = w1.x - __builtin_bit_cast(float, b1.x & 0xffff0000u);   \
            float r5 = w1.y - __builtin_bit_cast(float, b1.y & 0xffff0000u);   \
            float r6 = w1.z - __builtin_bit_cast(float, b1.z & 0xffff0000u);   \
            float r7 = w1.w - __builtin_bit_cast(float, b1.w & 0xffff0000u);   \
            al.x = cvtpk(r0, r1);                                              \
            al.y = cvtpk(r2, r3);                                              \
            al.z = cvtpk(r4, r5);                                              \
            al.w = cvtpk(r6, r7);                                              \
            u32x4 aw;                                                          \
            aw.x = loHalf ? al.x : ah.x;                                       \
            aw.y = loHalf ? al.y : ah.y;                                       \
            aw.z = loHalf ? al.z : ah.z;                                       \
            aw.w = loHalf ? al.w : ah.w;                                       \
            short8v afrag = __builtin_bit_cast(short8v, aw);                   \
            int xaddr = ((l & 15) * 512 + i * 32 + ko * 16) ^ (((l & 15) & 7) << 4); \
            short8v bfrag = *(const short8v*)((const char*)xs + xaddr);        \
            f32x4 acc = __builtin_amdgcn_mfma_f32_16x16x32_bf16(               \
                afrag, bfrag, (f32x4){0.f, 0.f, 0.f, 0.f}, 0, 0, 0);           \
            s0v += acc;                                                        \
            pk[i * 2]     = cvtpk(acc[0], acc[1]);                             \
            pk[i * 2 + 1] = cvtpk(acc[2], acc[3]);                             \
        } }

    f32x4 wA[8], wB[8];
    LOADG(wA, 0)
    LOADG(wB, 1)
    COMPG(wA, 0)
    LOADG(wA, 2)
    COMPG(wB, 1)
    LOADG(wB, 3)
    COMPG(wA, 2)
    COMPG(wB, 3)
#undef LOADG
#undef COMPG

    // ---- s0 partials (register-only), then fully-coalesced xh stores
    size_t pidx = (((size_t)ib * B_ + (l & 15)) * N_ + n) * 64 + mt * 16 + (l >> 4) * 4;
    *(f32x4*)(part + pidx) = s0v;

    #pragma unroll
    for (int i = 0; i < TI; ++i) {
        u32x2 v;
        v.x = pk[i * 2];
        v.y = pk[i * 2 + 1];
        size_t off = (size_t)(n * I_ + i0 + i) * 1024 + (size_t)t * 4;  // mt*256 + 4*l
        *reinterpret_cast<u32x2*>(xh2 + off) = v;
    }
}

// K2: coef = squash(mean over i of x_hat) — routing iteration 0.
// part layout [ib][b][n][d]; t packs (b,n,d) = coef index.
__global__ __launch_bounds__(256) void k_out0(const float* __restrict__ part,
                                              float* __restrict__ coef) {
    const int t = blockIdx.x * 256 + threadIdx.x;
    float s = 0.0f;
    for (int j = 0; j < IB; ++j) s += part[(size_t)j * BND + t];
    s *= (1.0f / (float)I_);
    coef[t] = squash1(s);
}

// K3: routing partial pass. xh2 tile is lane-ordered: thread t owns element
// offset 4t per i-tile => wave reads 512B CONTIGUOUS per i. Thread coords:
// b = t&15, d0 = (t>>4)*4. |logit|<=~50 -> exp2 safe without max-tracking.
// part2 layout [ic][n][b][d][2] = {z,a}.
__global__ __launch_bounds__(256) void k_rpart(const unsigned short* __restrict__ xh2,
                                               const float* __restrict__ coef,
                                               float* __restrict__ part2) {
    const int bx = blockIdx.x;
    const int n  = bx >> 4;
    const int ic = bx & 15;
    const int t  = threadIdx.x;
    const int b  = t & 15;
    const int d0 = (t >> 4) * 4;

    const unsigned short* base = xh2 + ((size_t)n * I_ + (size_t)ic * (I_ / IC)) * 1024
                               + (size_t)t * 4;
    f32x4 c4 = *(const f32x4*)(coef + ((size_t)b * N_ + n) * 64 + d0);
    float c2[4] = {c4.x * LOG2E, c4.y * LOG2E, c4.z * LOG2E, c4.w * LOG2E};
    float z[4] = {0, 0, 0, 0}, a[4] = {0, 0, 0, 0};

    #pragma unroll 8
    for (int i = 0; i < I_ / IC; ++i) {
        u32x2 u = *(const u32x2*)(base + (size_t)i * 1024);
        unsigned short s4[4] = {(unsigned short)(u.x & 0xffffu), (unsigned short)(u.x >> 16),
                                (unsigned short)(u.y & 0xffffu), (unsigned short)(u.y >> 16)};
        #pragma unroll
        for (int j = 0; j < 4; ++j) {
            float x = bff(s4[j]);
            float e = EXP2(x * c2[j]);
            z[j] += e;
            a[j] = fmaf(e, x, a[j]);
        }
    }

    size_t pidx = ((((size_t)ic * N_ + n) * 16 + b) * 64 + d0) * 2;
    f32x4 v0 = {z[0], a[0], z[1], a[1]};
    f32x4 v1 = {z[2], a[2], z[3], a[3]};
    *(f32x4*)(part2 + pidx)     = v0;
    *(f32x4*)(part2 + pidx + 4) = v1;
}

// K4: routing finisher. gid packs (n,b,d) matching part2 inner order.
// final=0: coef += squash(a/z). final=1: out[b][n][d] = squash(a/z).
__global__ __launch_bounds__(256) void k_rfin(const float* __restrict__ part2,
                                              const float* __restrict__ coefIn,
                                              float* __restrict__ outp,
                                              int final_) {
    const int gid = blockIdx.x * 256 + threadIdx.x;     // n*1024 + b*64 + d
    float Z = 0.0f, A = 0.0f;
    #pragma unroll
    for (int ic = 0; ic < IC; ++ic) {
        const float* p = part2 + ((size_t)ic * BND + gid) * 2;
        Z += p[0];
        A += p[1];
    }
    const int d = gid & 63, b = (gid >> 6) & 15, n = gid >> 10;
    const int ci = (b * N_ + n) * D_ + d;
    float o = squash1(A / Z);
    outp[ci] = final_ ? o : (coefIn[ci] + o);
}

extern "C" void kernel_launch(void* const* d_in, const int* in_sizes, int n_in,
                              void* d_out, int out_size, void* d_ws, size_t ws_size,
                              hipStream_t stream) {
    const float* inp = (const float*)d_in[0];
    const float* W   = (const float*)d_in[1];
    float* out = (float*)d_out;

    unsigned short* xh2 = (unsigned short*)d_ws;                    // 75,497,472 B
    float* part  = (float*)((char*)d_ws + 75497472);                //  9,437,184 B
    float* part2 = (float*)((char*)d_ws + 84934656);                //  4,194,304 B
    float* coef  = (float*)((char*)d_ws + 89128960);                //    131,072 B

    k_xhat<<<dim3(N_ * IB), dim3(256), 0, stream>>>(inp, W, xh2, part);
    k_out0<<<dim3(BND / 256), dim3(256), 0, stream>>>(part, coef);
    k_rpart<<<dim3(N_ * IC), dim3(256), 0, stream>>>(xh2, coef, part2);
    k_rfin <<<dim3(BND / 256), dim3(256), 0, stream>>>(part2, coef, coef, 0);
    k_rpart<<<dim3(N_ * IC), dim3(256), 0, stream>>>(xh2, coef, part2);
    k_rfin <<<dim3(BND / 256), dim3(256), 0, stream>>>(part2, coef, out, 1);
}